// Round 1
// baseline (523.731 us; speedup 1.0000x reference)
//
#include <hip/hip_runtime.h>

// MoE: B=4,S=2048 -> T=8192 tokens, D=1024, H=2048, O=1024, E=8, K=2
#define T_TOKENS 8192
#define D_DIM 1024
#define H_DIM 2048
#define O_DIM 1024
#define E_NUM 8
#define NPAIR 16384   // T_TOKENS * 2
#define GY_MAX 136    // >= max possible sum ceil(ne/128) = 135

typedef unsigned short u16;
typedef __bf16 bf16x8 __attribute__((ext_vector_type(8)));
typedef float f32x4 __attribute__((ext_vector_type(4)));

__device__ inline u16 f2bf(float f) {
  union { float f; unsigned u; } v; v.f = f;
  unsigned r = v.u + 0x7FFFu + ((v.u >> 16) & 1u);   // RNE
  return (u16)(r >> 16);
}

// async 16B global -> LDS (deposits at wave-uniform base + lane*16)
__device__ __forceinline__ void gload16(const u16* g, u16* l) {
  __builtin_amdgcn_global_load_lds((const __attribute__((address_space(1))) void*)g,
                                   (__attribute__((address_space(3))) void*)l, 16, 0, 0);
}

// ---------------- prep: transpose+cast weights: [E,R,C] f32 -> [E,C,R] bf16 ----
__global__ void transpose_cvt_kernel(const float* __restrict__ w, u16* __restrict__ wt,
                                     int R, int C) {
  __shared__ float tile[32][33];
  int e = blockIdx.z;
  int c0 = blockIdx.x * 32, r0 = blockIdx.y * 32;
  const float* wp = w + (size_t)e * R * C;
  u16* wtp = wt + (size_t)e * R * C;
  int tx = threadIdx.x, ty = threadIdx.y;  // (32,8)
  #pragma unroll
  for (int j = 0; j < 32; j += 8)
    tile[ty + j][tx] = wp[(size_t)(r0 + ty + j) * C + c0 + tx];
  __syncthreads();
  #pragma unroll
  for (int j = 0; j < 32; j += 8)
    wtp[(size_t)(c0 + ty + j) * R + r0 + tx] = f2bf(tile[tx][ty + j]);
}

// ---------------- gating + x->bf16 cast fused (NO atomics) ----------------
__global__ void gate_kernel(const float* __restrict__ x, const float* __restrict__ gw,
                            const float* __restrict__ gb, int* __restrict__ topk_idx,
                            float* __restrict__ topk_val, u16* __restrict__ xb) {
  int t = blockIdx.x * 4 + (threadIdx.x >> 6);   // one wave per token
  int lane = threadIdx.x & 63;
  const float4* xr4 = (const float4*)(x + (size_t)t * D_DIM);
  const float4* gw4 = (const float4*)gw;
  u16* xbr = xb + (size_t)t * D_DIM;
  float acc[E_NUM];
  #pragma unroll
  for (int e = 0; e < E_NUM; e++) acc[e] = 0.f;
  #pragma unroll
  for (int it = 0; it < D_DIM / 256; ++it) {
    float4 xv = xr4[it * 64 + lane];
    ushort4 o;
    o.x = f2bf(xv.x); o.y = f2bf(xv.y); o.z = f2bf(xv.z); o.w = f2bf(xv.w);
    *(ushort4*)(xbr + (it * 64 + lane) * 4) = o;
    #pragma unroll
    for (int e = 0; e < E_NUM; e++) {
      float4 wv = gw4[e * (D_DIM / 4) + it * 64 + lane];
      acc[e] += xv.x * wv.x + xv.y * wv.y + xv.z * wv.z + xv.w * wv.w;
    }
  }
  #pragma unroll
  for (int e = 0; e < E_NUM; e++) {
    #pragma unroll
    for (int o = 32; o > 0; o >>= 1) acc[e] += __shfl_down(acc[e], o);
  }
  if (lane == 0) {
    float l[E_NUM], mx = -1e30f;
    #pragma unroll
    for (int e = 0; e < E_NUM; e++) { l[e] = acc[e] + gb[e]; mx = fmaxf(mx, l[e]); }
    float p[E_NUM], s = 0.f;
    #pragma unroll
    for (int e = 0; e < E_NUM; e++) { p[e] = expf(l[e] - mx); s += p[e]; }
    float inv = 1.f / s;
    int i1 = 0;
    #pragma unroll
    for (int e = 1; e < E_NUM; e++) if (p[e] > p[i1]) i1 = e;   // strict >: lowest idx on tie
    int i2 = (i1 == 0) ? 1 : 0;
    #pragma unroll
    for (int e = 0; e < E_NUM; e++) if (e != i1 && e != i2 && p[e] > p[i2]) i2 = e;
    topk_idx[t * 2] = i1;     topk_idx[t * 2 + 1] = i2;
    topk_val[t * 2] = p[i1] * inv; topk_val[t * 2 + 1] = p[i2] * inv;
  }
}

// ---------------- histogram + scan + tile table: 1 block ----------------
__global__ void histscan_kernel(const int* __restrict__ topk_idx,
                                int* __restrict__ counts, int* __restrict__ eoff,
                                int* __restrict__ nblk, int* __restrict__ tbl_e,
                                int* __restrict__ tbl_m0) {
  __shared__ int wh[4][E_NUM];
  int tid = threadIdx.x;           // 256 threads
  int lane = tid & 63, wave = tid >> 6;
  int myc = 0;                     // lane e (<8) accumulates count of expert e
  for (int i = tid; i < NPAIR; i += 256) {
    int e = topk_idx[i];
    #pragma unroll
    for (int ee = 0; ee < E_NUM; ee++) {
      unsigned long long m = __ballot(e == ee);
      if (lane == ee) myc += __popcll(m);
    }
  }
  if (lane < E_NUM) wh[wave][lane] = myc;
  __syncthreads();
  if (tid == 0) {
    int s = 0, cl[E_NUM];
    for (int e = 0; e < E_NUM; e++) {
      int c = wh[0][e] + wh[1][e] + wh[2][e] + wh[3][e];
      counts[e] = c;
      cl[e] = c;
      eoff[e] = s;
      s += c;
    }
    eoff[E_NUM] = s;
    // flattened M-tile table shared by gemm1/gemm2 (BM=128)
    int nb = 0;
    for (int e = 0; e < E_NUM; e++)
      for (int m0 = 0; m0 < cl[e]; m0 += 128) { tbl_e[nb] = e; tbl_m0[nb] = m0; nb++; }
    nblk[0] = nb;   // <= 135
  }
}

// ---------------- scatter: per-block LDS agg + padded global cursors ----------------
__global__ void scatter_kernel(const int* __restrict__ topk_idx, const float* __restrict__ topk_val,
                               const int* __restrict__ eoff, int* __restrict__ cursor_pad,
                               int* __restrict__ pair_token, float* __restrict__ pair_gate) {
  __shared__ int lhist[E_NUM];
  __shared__ int lbase[E_NUM];
  int tid = threadIdx.x;
  int t = blockIdx.x * 256 + tid;
  if (tid < E_NUM) lhist[tid] = 0;
  __syncthreads();
  int e0 = topk_idx[t * 2], e1 = topk_idx[t * 2 + 1];
  int r0 = atomicAdd(&lhist[e0], 1);
  int r1 = atomicAdd(&lhist[e1], 1);
  __syncthreads();
  if (tid < E_NUM) lbase[tid] = eoff[tid] + atomicAdd(&cursor_pad[tid * 32], lhist[tid]);
  __syncthreads();
  int p0 = lbase[e0] + r0;
  int p1 = lbase[e1] + r1;
  pair_token[p0] = t; pair_gate[p0] = topk_val[t * 2];
  pair_token[p1] = t; pair_gate[p1] = topk_val[t * 2 + 1];
}

// BK=64 double-buffered GEMM. LDS layout: row stride 64 u16 (128B); 16B chunk
// g of row r stored at slot (g ^ (r&7)) -> conflict-free ds_read_b128 and clean
// global_load_lds lane-contiguous deposit. 2-phase pipeline: next tile's
// global_load_lds issued BEFORE current tile's compute; one barrier per tile
// (compiler's vmcnt(0)+lgkmcnt(0) drain at the barrier retires the prefetch,
// which by then has overlapped with ds_read+32 MFMA of the current tile).
// Grid is flattened through the histscan tile table (no empty blocks) and
// XCD-chunk-swizzled (bijective: nwg % 8 == 0 by construction).

// ---------------- GEMM1: h = relu(x[tok] @ w1[e] + b1[e]) -> hbuf bf16 ----------------
__global__ __launch_bounds__(256, 2) void gemm1_kernel(
    const u16* __restrict__ xb, const u16* __restrict__ w1t, const float* __restrict__ b1,
    const int* __restrict__ pair_token, const int* __restrict__ eoff,
    const int* __restrict__ ecnt, const int* __restrict__ nblk,
    const int* __restrict__ tbl_e, const int* __restrict__ tbl_m0,
    u16* __restrict__ hbuf) {
  // XCD-chunk swizzle over nwg = 16*GY_MAX = 2176 (chunk 272)
  int lin = blockIdx.y * 16 + blockIdx.x;
  int swz = (lin & 7) * (16 * GY_MAX / 8) + (lin >> 3);
  const int bx = swz & 15;
  const int yb = swz >> 4;
  if (yb >= nblk[0]) return;
  const int e = tbl_e[yb];
  const int m0t = tbl_m0[yb];
  const int ne = ecnt[e];
  const int off = eoff[e];
  const int n0 = bx * 128;

  __shared__ __align__(16) u16 As0[128 * 64], As1[128 * 64];
  __shared__ __align__(16) u16 Bs0[128 * 64], Bs1[128 * 64];

  const int tid = threadIdx.x;
  const int wid = tid >> 6;
  const int lane = tid & 63;

  // staging: wave wid covers rows [wid*32, wid*32+32), 4 issues of 8 rows
  const int strow8 = lane >> 3;          // 0..7
  const int slot = lane & 7;             // physical 16B slot within row
  const u16* aptr[4]; const u16* bptr[4];
  #pragma unroll
  for (int j = 0; j < 4; j++) {
    int r = wid * 32 + j * 8 + strow8;
    int gm = m0t + r;
    int tok = (gm < ne) ? pair_token[off + gm] : 0;
    int gl = slot ^ (r & 7);             // logical chunk this lane fetches
    aptr[j] = xb + (size_t)tok * D_DIM + gl * 8;
    bptr[j] = w1t + ((size_t)e * H_DIM + (n0 + r)) * D_DIM + gl * 8;
  }

  const int wm = (wid & 1) * 64;
  const int wn = (wid >> 1) * 64;
  const int lrow = lane & 15;
  const int quad = lane >> 4;
  const int pg0 = quad ^ (lrow & 7);            // k-half 0 physical slot
  const int pg1 = (quad + 4) ^ (lrow & 7);      // k-half 1 physical slot

  f32x4 acc[4][4] = {};

  auto STAGE = [&](u16* A_, u16* B_, int kk) {
    #pragma unroll
    for (int j = 0; j < 4; j++) {
      gload16(aptr[j] + kk, A_ + wid * 2048 + j * 512);
      gload16(bptr[j] + kk, B_ + wid * 2048 + j * 512);
    }
  };
  auto COMPUTE = [&](const u16* A_, const u16* B_) {
    bf16x8 af[4], bfr[4];
    #pragma unroll
    for (int i = 0; i < 4; i++) af[i] = *(const bf16x8*)&A_[(wm + i * 16 + lrow) * 64 + pg0 * 8];
    #pragma unroll
    for (int j = 0; j < 4; j++) bfr[j] = *(const bf16x8*)&B_[(wn + j * 16 + lrow) * 64 + pg0 * 8];
    #pragma unroll
    for (int i = 0; i < 4; i++)
      #pragma unroll
      for (int j = 0; j < 4; j++)
        acc[i][j] = __builtin_amdgcn_mfma_f32_16x16x32_bf16(af[i], bfr[j], acc[i][j], 0, 0, 0);
    #pragma unroll
    for (int i = 0; i < 4; i++) af[i] = *(const bf16x8*)&A_[(wm + i * 16 + lrow) * 64 + pg1 * 8];
    #pragma unroll
    for (int j = 0; j < 4; j++) bfr[j] = *(const bf16x8*)&B_[(wn + j * 16 + lrow) * 64 + pg1 * 8];
    #pragma unroll
    for (int i = 0; i < 4; i++)
      #pragma unroll
      for (int j = 0; j < 4; j++)
        acc[i][j] = __builtin_amdgcn_mfma_f32_16x16x32_bf16(af[i], bfr[j], acc[i][j], 0, 0, 0);
  };

  STAGE(As0, Bs0, 0);
  __syncthreads();
  for (int k0 = 0; k0 < D_DIM; k0 += 128) {
    if (k0 + 64 < D_DIM) STAGE(As1, Bs1, k0 + 64);
    COMPUTE(As0, Bs0);
    __syncthreads();
    if (k0 + 128 < D_DIM) STAGE(As0, Bs0, k0 + 128);
    COMPUTE(As1, Bs1);
    __syncthreads();
  }

  // epilogue: +b1, relu, bf16 store. C/D: col=lane&15, row=quad*4+reg
  #pragma unroll
  for (int i = 0; i < 4; i++) {
    #pragma unroll
    for (int r = 0; r < 4; r++) {
      int m = wm + i * 16 + quad * 4 + r;
      int gm = m0t + m;
      if (gm >= ne) continue;
      size_t rowbase = (size_t)(off + gm) * H_DIM;
      #pragma unroll
      for (int j = 0; j < 4; j++) {
        int n = n0 + wn + j * 16 + lrow;
        float v = acc[i][j][r] + b1[e * H_DIM + n];
        v = v > 0.f ? v : 0.f;
        hbuf[rowbase + n] = f2bf(v);
      }
    }
  }
}

// ---------------- GEMM2: out[tok] += gate * (h @ w2[e] + b2[e]) ----------------
__global__ __launch_bounds__(256, 2) void gemm2_kernel(
    const u16* __restrict__ hbuf, const u16* __restrict__ w2t, const float* __restrict__ b2,
    const int* __restrict__ pair_token, const float* __restrict__ pair_gate,
    const int* __restrict__ eoff, const int* __restrict__ ecnt,
    const int* __restrict__ nblk, const int* __restrict__ tbl_e,
    const int* __restrict__ tbl_m0, float* __restrict__ out) {
  // XCD-chunk swizzle over nwg = 8*GY_MAX = 1088 (chunk 136)
  int lin = blockIdx.y * 8 + blockIdx.x;
  int swz = (lin & 7) * (8 * GY_MAX / 8) + (lin >> 3);
  const int bx = swz & 7;
  const int yb = swz >> 3;
  if (yb >= nblk[0]) return;
  const int e = tbl_e[yb];
  const int m0t = tbl_m0[yb];
  const int ne = ecnt[e];
  const int off = eoff[e];
  const int n0 = bx * 128;

  __shared__ __align__(16) u16 As0[128 * 64], As1[128 * 64];
  __shared__ __align__(16) u16 Bs0[128 * 64], Bs1[128 * 64];

  const int tid = threadIdx.x;
  const int wid = tid >> 6;
  const int lane = tid & 63;

  const int strow8 = lane >> 3;
  const int slot = lane & 7;
  const u16* aptr[4]; const u16* bptr[4];
  #pragma unroll
  for (int j = 0; j < 4; j++) {
    int r = wid * 32 + j * 8 + strow8;
    int gl = slot ^ (r & 7);
    // hbuf has 128 slack rows past NPAIR; out-of-range rows discarded in epilogue
    aptr[j] = hbuf + (size_t)(off + m0t + r) * H_DIM + gl * 8;
    bptr[j] = w2t + ((size_t)e * O_DIM + (n0 + r)) * H_DIM + gl * 8;
  }

  const int wm = (wid & 1) * 64;
  const int wn = (wid >> 1) * 64;
  const int lrow = lane & 15;
  const int quad = lane >> 4;
  const int pg0 = quad ^ (lrow & 7);
  const int pg1 = (quad + 4) ^ (lrow & 7);

  f32x4 acc[4][4] = {};

  auto STAGE = [&](u16* A_, u16* B_, int kk) {
    #pragma unroll
    for (int j = 0; j < 4; j++) {
      gload16(aptr[j] + kk, A_ + wid * 2048 + j * 512);
      gload16(bptr[j] + kk, B_ + wid * 2048 + j * 512);
    }
  };
  auto COMPUTE = [&](const u16* A_, const u16* B_) {
    bf16x8 af[4], bfr[4];
    #pragma unroll
    for (int i = 0; i < 4; i++) af[i] = *(const bf16x8*)&A_[(wm + i * 16 + lrow) * 64 + pg0 * 8];
    #pragma unroll
    for (int j = 0; j < 4; j++) bfr[j] = *(const bf16x8*)&B_[(wn + j * 16 + lrow) * 64 + pg0 * 8];
    #pragma unroll
    for (int i = 0; i < 4; i++)
      #pragma unroll
      for (int j = 0; j < 4; j++)
        acc[i][j] = __builtin_amdgcn_mfma_f32_16x16x32_bf16(af[i], bfr[j], acc[i][j], 0, 0, 0);
    #pragma unroll
    for (int i = 0; i < 4; i++) af[i] = *(const bf16x8*)&A_[(wm + i * 16 + lrow) * 64 + pg1 * 8];
    #pragma unroll
    for (int j = 0; j < 4; j++) bfr[j] = *(const bf16x8*)&B_[(wn + j * 16 + lrow) * 64 + pg1 * 8];
    #pragma unroll
    for (int i = 0; i < 4; i++)
      #pragma unroll
      for (int j = 0; j < 4; j++)
        acc[i][j] = __builtin_amdgcn_mfma_f32_16x16x32_bf16(af[i], bfr[j], acc[i][j], 0, 0, 0);
  };

  STAGE(As0, Bs0, 0);
  __syncthreads();
  for (int k0 = 0; k0 < H_DIM; k0 += 128) {
    if (k0 + 64 < H_DIM) STAGE(As1, Bs1, k0 + 64);
    COMPUTE(As0, Bs0);
    __syncthreads();
    if (k0 + 128 < H_DIM) STAGE(As0, Bs0, k0 + 128);
    COMPUTE(As1, Bs1);
    __syncthreads();
  }

  #pragma unroll
  for (int i = 0; i < 4; i++) {
    #pragma unroll
    for (int r = 0; r < 4; r++) {
      int m = wm + i * 16 + quad * 4 + r;
      int gm = m0t + m;
      if (gm >= ne) continue;
      int pair = off + gm;
      int tok = pair_token[pair];
      float g = pair_gate[pair];
      #pragma unroll
      for (int j = 0; j < 4; j++) {
        int n = n0 + wn + j * 16 + lrow;
        float v = (acc[i][j][r] + b2[e * O_DIM + n]) * g;
        atomicAdd(&out[(size_t)tok * O_DIM + n], v);
      }
    }
  }
}

extern "C" void kernel_launch(void* const* d_in, const int* in_sizes, int n_in,
                              void* d_out, int out_size, void* d_ws, size_t ws_size,
                              hipStream_t stream) {
  const float* x  = (const float*)d_in[0];
  const float* gw = (const float*)d_in[1];
  const float* gb = (const float*)d_in[2];
  const float* w1 = (const float*)d_in[3];
  const float* b1 = (const float*)d_in[4];
  const float* w2 = (const float*)d_in[5];
  const float* b2 = (const float*)d_in[6];
  float* out = (float*)d_out;

  char* ws = (char*)d_ws;
  size_t off = 0;
  auto take = [&](size_t bytes) -> char* {
    char* p = ws + off;
    off = (off + bytes + 255) & ~(size_t)255;
    return p;
  };
  int*   meta       = (int*)take(4096);  // cursor_pad[256] | counts[8] | eoff[9] | nblk | tbl_e[136] | tbl_m0[136]
  int*   cursor_pad = meta;
  int*   counts     = meta + 256;
  int*   eoff       = meta + 264;
  int*   nblk       = meta + 273;
  int*   tbl_e      = meta + 274;
  int*   tbl_m0     = meta + 410;
  int*   topk_idx   = (int*)take((size_t)T_TOKENS * 2 * 4);
  float* topk_val   = (float*)take((size_t)T_TOKENS * 2 * 4);
  int*   pair_token = (int*)take((size_t)(NPAIR + 256) * 4);
  float* pair_gate  = (float*)take((size_t)(NPAIR + 256) * 4);
  u16*   xb         = (u16*)take((size_t)T_TOKENS * D_DIM * 2);
  u16*   w1t        = (u16*)take((size_t)E_NUM * D_DIM * H_DIM * 2);
  u16*   w2t        = (u16*)take((size_t)E_NUM * H_DIM * O_DIM * 2);
  u16*   hbuf       = (u16*)take((size_t)(NPAIR + 128) * H_DIM * 2);

  hipMemsetAsync(meta, 0, 4096, stream);
  hipMemsetAsync(out, 0, (size_t)T_TOKENS * O_DIM * 4, stream);

  transpose_cvt_kernel<<<dim3(H_DIM / 32, D_DIM / 32, E_NUM), dim3(32, 8), 0, stream>>>(w1, w1t, D_DIM, H_DIM);
  transpose_cvt_kernel<<<dim3(O_DIM / 32, H_DIM / 32, E_NUM), dim3(32, 8), 0, stream>>>(w2, w2t, H_DIM, O_DIM);
  gate_kernel<<<T_TOKENS / 4, 256, 0, stream>>>(x, gw, gb, topk_idx, topk_val, xb);
  histscan_kernel<<<1, 256, 0, stream>>>(topk_idx, counts, eoff, nblk, tbl_e, tbl_m0);
  scatter_kernel<<<T_TOKENS / 256, 256, 0, stream>>>(topk_idx, topk_val, eoff, cursor_pad, pair_token, pair_gate);
  gemm1_kernel<<<dim3(16, GY_MAX), 256, 0, stream>>>(xb, w1t, b1, pair_token, eoff, counts, nblk, tbl_e, tbl_m0, hbuf);
  gemm2_kernel<<<dim3(8, GY_MAX), 256, 0, stream>>>(hbuf, w2t, b2, pair_token, pair_gate, eoff, counts, nblk, tbl_e, tbl_m0, out);
}

// Round 2
// 498.836 us; speedup vs baseline: 1.0499x; 1.0499x over previous
//
#include <hip/hip_runtime.h>

// MoE: B=4,S=2048 -> T=8192 tokens, D=1024, H=2048, O=1024, E=8, K=2
#define T_TOKENS 8192
#define D_DIM 1024
#define H_DIM 2048
#define O_DIM 1024
#define E_NUM 8
#define NPAIR 16384   // T_TOKENS * 2
#define GY_MAX 136    // >= max possible sum ceil(ne/128) = 135

typedef unsigned short u16;
typedef __bf16 bf16x8 __attribute__((ext_vector_type(8)));
typedef float f32x4 __attribute__((ext_vector_type(4)));

// counted waitcnt: loads stay in flight across barriers (AITER pattern, never
// drain to 0 in the main loop). Literal immediate via token paste.
#define VMCNT(n) asm volatile("s_waitcnt vmcnt(" #n ")" ::: "memory")

__device__ __forceinline__ void barsync() {
  asm volatile("" ::: "memory");
  __builtin_amdgcn_s_barrier();
  __builtin_amdgcn_sched_barrier(0);
}

__device__ inline u16 f2bf(float f) {
  union { float f; unsigned u; } v; v.f = f;
  unsigned r = v.u + 0x7FFFu + ((v.u >> 16) & 1u);   // RNE
  return (u16)(r >> 16);
}

// async 16B global -> LDS (deposits at wave-uniform base + lane*16)
__device__ __forceinline__ void gload16(const u16* g, u16* l) {
  __builtin_amdgcn_global_load_lds((const __attribute__((address_space(1))) void*)g,
                                   (__attribute__((address_space(3))) void*)l, 16, 0, 0);
}

// ---------------- prep: transpose+cast weights: [E,R,C] f32 -> [E,C,R] bf16 ----
__global__ void transpose_cvt_kernel(const float* __restrict__ w, u16* __restrict__ wt,
                                     int R, int C) {
  __shared__ float tile[32][33];
  int e = blockIdx.z;
  int c0 = blockIdx.x * 32, r0 = blockIdx.y * 32;
  const float* wp = w + (size_t)e * R * C;
  u16* wtp = wt + (size_t)e * R * C;
  int tx = threadIdx.x, ty = threadIdx.y;  // (32,8)
  #pragma unroll
  for (int j = 0; j < 32; j += 8)
    tile[ty + j][tx] = wp[(size_t)(r0 + ty + j) * C + c0 + tx];
  __syncthreads();
  #pragma unroll
  for (int j = 0; j < 32; j += 8)
    wtp[(size_t)(c0 + ty + j) * R + r0 + tx] = f2bf(tile[tx][ty + j]);
}

// ---------------- gating + x->bf16 cast fused (NO atomics) ----------------
__global__ void gate_kernel(const float* __restrict__ x, const float* __restrict__ gw,
                            const float* __restrict__ gb, int* __restrict__ topk_idx,
                            float* __restrict__ topk_val, u16* __restrict__ xb) {
  int t = blockIdx.x * 4 + (threadIdx.x >> 6);   // one wave per token
  int lane = threadIdx.x & 63;
  const float4* xr4 = (const float4*)(x + (size_t)t * D_DIM);
  const float4* gw4 = (const float4*)gw;
  u16* xbr = xb + (size_t)t * D_DIM;
  float acc[E_NUM];
  #pragma unroll
  for (int e = 0; e < E_NUM; e++) acc[e] = 0.f;
  #pragma unroll
  for (int it = 0; it < D_DIM / 256; ++it) {
    float4 xv = xr4[it * 64 + lane];
    ushort4 o;
    o.x = f2bf(xv.x); o.y = f2bf(xv.y); o.z = f2bf(xv.z); o.w = f2bf(xv.w);
    *(ushort4*)(xbr + (it * 64 + lane) * 4) = o;
    #pragma unroll
    for (int e = 0; e < E_NUM; e++) {
      float4 wv = gw4[e * (D_DIM / 4) + it * 64 + lane];
      acc[e] += xv.x * wv.x + xv.y * wv.y + xv.z * wv.z + xv.w * wv.w;
    }
  }
  #pragma unroll
  for (int e = 0; e < E_NUM; e++) {
    #pragma unroll
    for (int o = 32; o > 0; o >>= 1) acc[e] += __shfl_down(acc[e], o);
  }
  if (lane == 0) {
    float l[E_NUM], mx = -1e30f;
    #pragma unroll
    for (int e = 0; e < E_NUM; e++) { l[e] = acc[e] + gb[e]; mx = fmaxf(mx, l[e]); }
    float p[E_NUM], s = 0.f;
    #pragma unroll
    for (int e = 0; e < E_NUM; e++) { p[e] = expf(l[e] - mx); s += p[e]; }
    float inv = 1.f / s;
    int i1 = 0;
    #pragma unroll
    for (int e = 1; e < E_NUM; e++) if (p[e] > p[i1]) i1 = e;   // strict >: lowest idx on tie
    int i2 = (i1 == 0) ? 1 : 0;
    #pragma unroll
    for (int e = 0; e < E_NUM; e++) if (e != i1 && e != i2 && p[e] > p[i2]) i2 = e;
    topk_idx[t * 2] = i1;     topk_idx[t * 2 + 1] = i2;
    topk_val[t * 2] = p[i1] * inv; topk_val[t * 2 + 1] = p[i2] * inv;
  }
}

// ---------------- histogram + scan + tile table: 1 block ----------------
__global__ void histscan_kernel(const int* __restrict__ topk_idx,
                                int* __restrict__ counts, int* __restrict__ eoff,
                                int* __restrict__ nblk, int* __restrict__ tbl_e,
                                int* __restrict__ tbl_m0) {
  __shared__ int wh[4][E_NUM];
  int tid = threadIdx.x;           // 256 threads
  int lane = tid & 63, wave = tid >> 6;
  int myc = 0;                     // lane e (<8) accumulates count of expert e
  for (int i = tid; i < NPAIR; i += 256) {
    int e = topk_idx[i];
    #pragma unroll
    for (int ee = 0; ee < E_NUM; ee++) {
      unsigned long long m = __ballot(e == ee);
      if (lane == ee) myc += __popcll(m);
    }
  }
  if (lane < E_NUM) wh[wave][lane] = myc;
  __syncthreads();
  if (tid == 0) {
    int s = 0, cl[E_NUM];
    for (int e = 0; e < E_NUM; e++) {
      int c = wh[0][e] + wh[1][e] + wh[2][e] + wh[3][e];
      counts[e] = c;
      cl[e] = c;
      eoff[e] = s;
      s += c;
    }
    eoff[E_NUM] = s;
    // flattened M-tile table shared by gemm1/gemm2 (BM=128)
    int nb = 0;
    for (int e = 0; e < E_NUM; e++)
      for (int m0 = 0; m0 < cl[e]; m0 += 128) { tbl_e[nb] = e; tbl_m0[nb] = m0; nb++; }
    nblk[0] = nb;   // <= 135
  }
}

// ---------------- scatter: per-block LDS agg + padded global cursors ----------------
__global__ void scatter_kernel(const int* __restrict__ topk_idx, const float* __restrict__ topk_val,
                               const int* __restrict__ eoff, int* __restrict__ cursor_pad,
                               int* __restrict__ pair_token, float* __restrict__ pair_gate) {
  __shared__ int lhist[E_NUM];
  __shared__ int lbase[E_NUM];
  int tid = threadIdx.x;
  int t = blockIdx.x * 256 + tid;
  if (tid < E_NUM) lhist[tid] = 0;
  __syncthreads();
  int e0 = topk_idx[t * 2], e1 = topk_idx[t * 2 + 1];
  int r0 = atomicAdd(&lhist[e0], 1);
  int r1 = atomicAdd(&lhist[e1], 1);
  __syncthreads();
  if (tid < E_NUM) lbase[tid] = eoff[tid] + atomicAdd(&cursor_pad[tid * 32], lhist[tid]);
  __syncthreads();
  int p0 = lbase[e0] + r0;
  int p1 = lbase[e1] + r1;
  pair_token[p0] = t; pair_gate[p0] = topk_val[t * 2];
  pair_token[p1] = t; pair_gate[p1] = topk_val[t * 2 + 1];
}

// ===================== GEMM core structure =====================
// BK=32, TRIPLE-buffered (48KB LDS -> 3 blocks/CU), counted-vmcnt pipeline:
//   prologue: stage tiles 0,1,2                      (12 loads/wave in flight)
//   iter t:   vmcnt(8)  [tile t landed; t+1,t+2 in flight]
//             s_barrier; compute(buf t%3); s_barrier; stage(t+3 -> buf t%3)
//   peel:     vmcnt(8)/(4)/(0) for last 3 tiles
// Race-free by construction: a buffer is only re-staged after the barrier that
// follows all waves' ds_reads of it; deposits of tile t are globally visible
// after (per-wave vmcnt >= own loads) + barrier.
//
// LDS layout: BK=32 rows (64B) pair-packed into 64 physical 128B rows.
// logical (row r, 16B-chunk c in 0..3) -> phys row p=r>>1, slot ((r&1)*4+c)^(p&7).
// global_load_lds deposits linearly (lane -> phys row p0+lane>>3, slot lane&7);
// the per-lane SOURCE address is pre-inverse-swizzled so the pair (deposit,
// ds_read) is the same involution -> 8-access/bank minimum, 0 conflicts.

// ---------------- GEMM1: h = relu(x[tok] @ w1[e] + b1[e]) -> hbuf bf16 ----------------
__global__ __launch_bounds__(256, 3) void gemm1_kernel(
    const u16* __restrict__ xb, const u16* __restrict__ w1t, const float* __restrict__ b1,
    const int* __restrict__ pair_token, const int* __restrict__ eoff,
    const int* __restrict__ ecnt, const int* __restrict__ nblk,
    const int* __restrict__ tbl_e, const int* __restrict__ tbl_m0,
    u16* __restrict__ hbuf) {
  // XCD-chunk swizzle over nwg = 16*GY_MAX = 2176 (chunk 272)
  int lin = blockIdx.y * 16 + blockIdx.x;
  int swz = (lin & 7) * (16 * GY_MAX / 8) + (lin >> 3);
  const int bx = swz & 15;
  const int yb = swz >> 4;
  if (yb >= nblk[0]) return;
  const int e = tbl_e[yb];
  const int m0t = tbl_m0[yb];
  const int ne = ecnt[e];
  const int off = eoff[e];
  const int n0 = bx * 128;

  // 3 buffers x (A 8KB + B 8KB) = 48KB
  __shared__ __align__(16) u16 SH[3 * 2 * 4096];

  const int tid = threadIdx.x;
  const int wid = tid >> 6;
  const int lane = tid & 63;

  // per-lane staging source addresses (inverse-swizzled), 2 issues each for A,B
  const u16* aptrA[2]; const u16* bptrB[2];
  #pragma unroll
  for (int j = 0; j < 2; j++) {
    int p = wid * 16 + j * 8 + (lane >> 3);      // phys row this lane deposits to
    int u = (lane & 7) ^ (p & 7);                // logical (r-parity, chunk)
    int r = 2 * p + (u >> 2);                    // logical tile row 0..127
    int c = u & 3;                               // 16B chunk within 32-elem row
    int gm = m0t + r;
    int tok = (gm < ne) ? pair_token[off + gm] : 0;
    aptrA[j] = xb + (size_t)tok * D_DIM + c * 8;
    bptrB[j] = w1t + ((size_t)e * H_DIM + (n0 + r)) * D_DIM + c * 8;
  }

  const int wm = (wid & 1) * 64;
  const int wn = (wid >> 1) * 64;
  const int lrow = lane & 15;
  const int quad = lane >> 4;

  f32x4 acc[4][4] = {};

  auto STAGE = [&](int buf, int k0) {
    u16* Ab = SH + buf * 8192;
    u16* Bb = Ab + 4096;
    #pragma unroll
    for (int j = 0; j < 2; j++) {
      gload16(aptrA[j] + k0, Ab + (wid * 16 + j * 8) * 64);
      gload16(bptrB[j] + k0, Bb + (wid * 16 + j * 8) * 64);
    }
  };
  auto COMPUTE = [&](int buf) {
    const u16* Ab = SH + buf * 8192;
    const u16* Bb = Ab + 4096;
    bf16x8 af[4], bfr[4];
    #pragma unroll
    for (int i = 0; i < 4; i++) {
      int r = wm + i * 16 + lrow;
      int p = r >> 1;
      int s = (((r & 1) << 2) | quad) ^ (p & 7);
      af[i] = *(const bf16x8*)&Ab[p * 64 + s * 8];
    }
    #pragma unroll
    for (int j = 0; j < 4; j++) {
      int r = wn + j * 16 + lrow;
      int p = r >> 1;
      int s = (((r & 1) << 2) | quad) ^ (p & 7);
      bfr[j] = *(const bf16x8*)&Bb[p * 64 + s * 8];
    }
    #pragma unroll
    for (int i = 0; i < 4; i++)
      #pragma unroll
      for (int j = 0; j < 4; j++)
        acc[i][j] = __builtin_amdgcn_mfma_f32_16x16x32_bf16(af[i], bfr[j], acc[i][j], 0, 0, 0);
  };

  // pipeline: NT = D_DIM/32 = 32 tiles
  STAGE(0, 0); STAGE(1, 32); STAGE(2, 64);
  int cur = 0;
  for (int t = 0; t < D_DIM / 32 - 3; ++t) {
    VMCNT(8);
    barsync();
    COMPUTE(cur);
    barsync();
    STAGE(cur, (t + 3) * 32);
    cur = (cur == 2) ? 0 : cur + 1;
  }
  VMCNT(8); barsync(); COMPUTE(cur); cur = (cur == 2) ? 0 : cur + 1;
  VMCNT(4); barsync(); COMPUTE(cur); cur = (cur == 2) ? 0 : cur + 1;
  VMCNT(0); barsync(); COMPUTE(cur);

  // epilogue: +b1, relu, bf16 store. C/D: col=lane&15, row=quad*4+reg
  #pragma unroll
  for (int i = 0; i < 4; i++) {
    #pragma unroll
    for (int r = 0; r < 4; r++) {
      int m = wm + i * 16 + quad * 4 + r;
      int gm = m0t + m;
      if (gm >= ne) continue;
      size_t rowbase = (size_t)(off + gm) * H_DIM;
      #pragma unroll
      for (int j = 0; j < 4; j++) {
        int n = n0 + wn + j * 16 + lrow;
        float v = acc[i][j][r] + b1[e * H_DIM + n];
        v = v > 0.f ? v : 0.f;
        hbuf[rowbase + n] = f2bf(v);
      }
    }
  }
}

// ---------------- GEMM2: out[tok] += gate * (h @ w2[e] + b2[e]) ----------------
__global__ __launch_bounds__(256, 3) void gemm2_kernel(
    const u16* __restrict__ hbuf, const u16* __restrict__ w2t, const float* __restrict__ b2,
    const int* __restrict__ pair_token, const float* __restrict__ pair_gate,
    const int* __restrict__ eoff, const int* __restrict__ ecnt,
    const int* __restrict__ nblk, const int* __restrict__ tbl_e,
    const int* __restrict__ tbl_m0, float* __restrict__ out) {
  // XCD-chunk swizzle over nwg = 8*GY_MAX = 1088 (chunk 136)
  int lin = blockIdx.y * 8 + blockIdx.x;
  int swz = (lin & 7) * (8 * GY_MAX / 8) + (lin >> 3);
  const int bx = swz & 7;
  const int yb = swz >> 3;
  if (yb >= nblk[0]) return;
  const int e = tbl_e[yb];
  const int m0t = tbl_m0[yb];
  const int ne = ecnt[e];
  const int off = eoff[e];
  const int n0 = bx * 128;

  __shared__ __align__(16) u16 SH[3 * 2 * 4096];

  const int tid = threadIdx.x;
  const int wid = tid >> 6;
  const int lane = tid & 63;

  const u16* aptrA[2]; const u16* bptrB[2];
  #pragma unroll
  for (int j = 0; j < 2; j++) {
    int p = wid * 16 + j * 8 + (lane >> 3);
    int u = (lane & 7) ^ (p & 7);
    int r = 2 * p + (u >> 2);
    int c = u & 3;
    // hbuf has 128 slack rows past NPAIR; out-of-range rows discarded in epilogue
    aptrA[j] = hbuf + (size_t)(off + m0t + r) * H_DIM + c * 8;
    bptrB[j] = w2t + ((size_t)e * O_DIM + (n0 + r)) * H_DIM + c * 8;
  }

  const int wm = (wid & 1) * 64;
  const int wn = (wid >> 1) * 64;
  const int lrow = lane & 15;
  const int quad = lane >> 4;

  f32x4 acc[4][4] = {};

  auto STAGE = [&](int buf, int k0) {
    u16* Ab = SH + buf * 8192;
    u16* Bb = Ab + 4096;
    #pragma unroll
    for (int j = 0; j < 2; j++) {
      gload16(aptrA[j] + k0, Ab + (wid * 16 + j * 8) * 64);
      gload16(bptrB[j] + k0, Bb + (wid * 16 + j * 8) * 64);
    }
  };
  auto COMPUTE = [&](int buf) {
    const u16* Ab = SH + buf * 8192;
    const u16* Bb = Ab + 4096;
    bf16x8 af[4], bfr[4];
    #pragma unroll
    for (int i = 0; i < 4; i++) {
      int r = wm + i * 16 + lrow;
      int p = r >> 1;
      int s = (((r & 1) << 2) | quad) ^ (p & 7);
      af[i] = *(const bf16x8*)&Ab[p * 64 + s * 8];
    }
    #pragma unroll
    for (int j = 0; j < 4; j++) {
      int r = wn + j * 16 + lrow;
      int p = r >> 1;
      int s = (((r & 1) << 2) | quad) ^ (p & 7);
      bfr[j] = *(const bf16x8*)&Bb[p * 64 + s * 8];
    }
    #pragma unroll
    for (int i = 0; i < 4; i++)
      #pragma unroll
      for (int j = 0; j < 4; j++)
        acc[i][j] = __builtin_amdgcn_mfma_f32_16x16x32_bf16(af[i], bfr[j], acc[i][j], 0, 0, 0);
  };

  // pipeline: NT = H_DIM/32 = 64 tiles
  STAGE(0, 0); STAGE(1, 32); STAGE(2, 64);
  int cur = 0;
  for (int t = 0; t < H_DIM / 32 - 3; ++t) {
    VMCNT(8);
    barsync();
    COMPUTE(cur);
    barsync();
    STAGE(cur, (t + 3) * 32);
    cur = (cur == 2) ? 0 : cur + 1;
  }
  VMCNT(8); barsync(); COMPUTE(cur); cur = (cur == 2) ? 0 : cur + 1;
  VMCNT(4); barsync(); COMPUTE(cur); cur = (cur == 2) ? 0 : cur + 1;
  VMCNT(0); barsync(); COMPUTE(cur);

  #pragma unroll
  for (int i = 0; i < 4; i++) {
    #pragma unroll
    for (int r = 0; r < 4; r++) {
      int m = wm + i * 16 + quad * 4 + r;
      int gm = m0t + m;
      if (gm >= ne) continue;
      int pair = off + gm;
      int tok = pair_token[pair];
      float g = pair_gate[pair];
      #pragma unroll
      for (int j = 0; j < 4; j++) {
        int n = n0 + wn + j * 16 + lrow;
        float v = (acc[i][j][r] + b2[e * O_DIM + n]) * g;
        atomicAdd(&out[(size_t)tok * O_DIM + n], v);
      }
    }
  }
}

extern "C" void kernel_launch(void* const* d_in, const int* in_sizes, int n_in,
                              void* d_out, int out_size, void* d_ws, size_t ws_size,
                              hipStream_t stream) {
  const float* x  = (const float*)d_in[0];
  const float* gw = (const float*)d_in[1];
  const float* gb = (const float*)d_in[2];
  const float* w1 = (const float*)d_in[3];
  const float* b1 = (const float*)d_in[4];
  const float* w2 = (const float*)d_in[5];
  const float* b2 = (const float*)d_in[6];
  float* out = (float*)d_out;

  char* ws = (char*)d_ws;
  size_t off = 0;
  auto take = [&](size_t bytes) -> char* {
    char* p = ws + off;
    off = (off + bytes + 255) & ~(size_t)255;
    return p;
  };
  int*   meta       = (int*)take(4096);  // cursor_pad[256] | counts[8] | eoff[9] | nblk | tbl_e[136] | tbl_m0[136]
  int*   cursor_pad = meta;
  int*   counts     = meta + 256;
  int*   eoff       = meta + 264;
  int*   nblk       = meta + 273;
  int*   tbl_e      = meta + 274;
  int*   tbl_m0     = meta + 410;
  int*   topk_idx   = (int*)take((size_t)T_TOKENS * 2 * 4);
  float* topk_val   = (float*)take((size_t)T_TOKENS * 2 * 4);
  int*   pair_token = (int*)take((size_t)(NPAIR + 256) * 4);
  float* pair_gate  = (float*)take((size_t)(NPAIR + 256) * 4);
  u16*   xb         = (u16*)take((size_t)T_TOKENS * D_DIM * 2);
  u16*   w1t        = (u16*)take((size_t)E_NUM * D_DIM * H_DIM * 2);
  u16*   w2t        = (u16*)take((size_t)E_NUM * H_DIM * O_DIM * 2);
  u16*   hbuf       = (u16*)take((size_t)(NPAIR + 128) * H_DIM * 2);

  hipMemsetAsync(meta, 0, 4096, stream);
  hipMemsetAsync(out, 0, (size_t)T_TOKENS * O_DIM * 4, stream);

  transpose_cvt_kernel<<<dim3(H_DIM / 32, D_DIM / 32, E_NUM), dim3(32, 8), 0, stream>>>(w1, w1t, D_DIM, H_DIM);
  transpose_cvt_kernel<<<dim3(O_DIM / 32, H_DIM / 32, E_NUM), dim3(32, 8), 0, stream>>>(w2, w2t, H_DIM, O_DIM);
  gate_kernel<<<T_TOKENS / 4, 256, 0, stream>>>(x, gw, gb, topk_idx, topk_val, xb);
  histscan_kernel<<<1, 256, 0, stream>>>(topk_idx, counts, eoff, nblk, tbl_e, tbl_m0);
  scatter_kernel<<<T_TOKENS / 256, 256, 0, stream>>>(topk_idx, topk_val, eoff, cursor_pad, pair_token, pair_gate);
  gemm1_kernel<<<dim3(16, GY_MAX), 256, 0, stream>>>(xb, w1t, b1, pair_token, eoff, counts, nblk, tbl_e, tbl_m0, hbuf);
  gemm2_kernel<<<dim3(8, GY_MAX), 256, 0, stream>>>(hbuf, w2t, b2, pair_token, pair_gate, eoff, counts, nblk, tbl_e, tbl_m0, out);
}